// Round 3
// baseline (1883.656 us; speedup 1.0000x reference)
//
#include <hip/hip_runtime.h>

// Problem constants (from reference)
#define NN  100000   // nodes
#define FIN 128      // in features
#define HID 256      // hidden
#define NE  600000   // edges
#define FEPS 1e-12f

// ---------------------------------------------------------------------------
// Workspace layout (all 4-byte elems, ~5.2 MB):
//   int   cnt[NN]     in-degree counts   (zeroed)
//   int   cur[NN]     fill cursors       (zeroed)
//   int   off[NN+1]   CSR row offsets (by dst)
//   int   col[NE]     CSR column = src node ids
//   float g[NN*2]     h1 @ W2_l^T (normalized)  -> mean-aggregated in layer 2
//   float r[NN*2]     h1 @ W2_r^T (normalized)  -> per-node term
//   int   flag[1]     1 if edge_index is int64-laid-out, 0 if int32
// ---------------------------------------------------------------------------

// Detect int64 vs int32 edge_index layout: under int64 (little-endian,
// values < 2^31) every odd 32-bit word is 0; under int32 the odd words are
// src[1],src[3],... (P(all 64 == 0) ~ 1e-320).
__global__ __launch_bounds__(64) void detect_kernel(
    const int* __restrict__ ei, int* __restrict__ flag)
{
    unsigned long long b = __ballot(ei[2 * threadIdx.x + 1] != 0);
    if (threadIdx.x == 0) *flag = (b == 0ULL) ? 1 : 0;
}

__device__ __forceinline__ int ld_src(const int* ei, int e, int f) {
    return f ? ei[2 * e] : ei[e];
}
__device__ __forceinline__ int ld_dst(const int* ei, int e, int f) {
    return f ? ei[2 * (NE + e)] : ei[NE + e];
}
__device__ __forceinline__ int clampN(int v) {
    return ((unsigned)v < (unsigned)NN) ? v : 0;
}

// Kernel 1: in-degree count.
__global__ __launch_bounds__(256) void count_kernel(
    const int* __restrict__ ei, const int* __restrict__ flag,
    int* __restrict__ cnt)
{
    int e = blockIdx.x * 256 + threadIdx.x;
    if (e >= NE) return;
    int f = *flag;
    atomicAdd(cnt + clampN(ld_dst(ei, e, f)), 1);
}

// Kernel 2: exclusive prefix sum of cnt -> off (single block, 1024 threads).
__global__ __launch_bounds__(1024) void scan_kernel(
    const int* __restrict__ cnt, int* __restrict__ off)
{
    __shared__ int sm[1024];
    const int CH = (NN + 1023) / 1024;   // 98
    int t = threadIdx.x;
    int base = t * CH;
    int s = 0;
    for (int i = 0; i < CH; ++i) {
        int idx = base + i;
        if (idx < NN) s += cnt[idx];
    }
    sm[t] = s;
    __syncthreads();
    for (int d = 1; d < 1024; d <<= 1) {
        int v = (t >= d) ? sm[t - d] : 0;
        __syncthreads();
        sm[t] += v;
        __syncthreads();
    }
    int run = sm[t] - s;                 // exclusive prefix of this chunk
    for (int i = 0; i < CH; ++i) {
        int idx = base + i;
        if (idx < NN) { off[idx] = run; run += cnt[idx]; }
    }
    if (t == 1023) off[NN] = sm[1023];   // == NE
}

// Kernel 3: place src ids into CSR slots.
__global__ __launch_bounds__(256) void fill_kernel(
    const int* __restrict__ ei, const int* __restrict__ flag,
    const int* __restrict__ off, int* __restrict__ cur, int* __restrict__ col)
{
    int e = blockIdx.x * 256 + threadIdx.x;
    if (e >= NE) return;
    int f = *flag;
    int src = clampN(ld_src(ei, e, f));
    int dst = clampN(ld_dst(ei, e, f));
    int p = atomicAdd(cur + dst, 1);
    col[off[dst] + p] = src;
}

// ---------------------------------------------------------------------------
// Kernel 4: fused layer-1 (+ layer-2 projections). One NODE per thread.
//   agg = mean of x[neighbors] (CSR gather, fp32 registers)
//   o[j] = b1[j] + agg . W1_l[j,:] + x . W1_r[j,:]
//   h = relu(o)/max(||o||,eps)        (relu(o/D) = relu(o)/D, D>0)
//   g[c] = h . W2_l[c,:];  r[c] = h . W2_r[c,:]
// a[128]+xr[128] register-resident (~290 VGPR, 1 wave/SIMD by design).
// ---------------------------------------------------------------------------
__global__ __launch_bounds__(256, 1) void layer1_kernel(
    const int* __restrict__ off, const int* __restrict__ col,
    const float* __restrict__ x,    // [NN, FIN]
    const float* __restrict__ W1l,  // [HID, FIN]
    const float* __restrict__ W1r,  // [HID, FIN]
    const float* __restrict__ b1,   // [HID]
    const float* __restrict__ W2l,  // [2, HID]
    const float* __restrict__ W2r,  // [2, HID]
    float* __restrict__ g,          // [NN, 2]
    float* __restrict__ r)          // [NN, 2]
{
    int n = blockIdx.x * 256 + threadIdx.x;
    if (n >= NN) return;

    int s0 = off[n], s1 = off[n + 1];

    float a[FIN];
#pragma unroll
    for (int i = 0; i < FIN; ++i) a[i] = 0.0f;

    for (int i = s0; i < s1; ++i) {
        int src = clampN(col[i]);
        const float4* xv = (const float4*)(x + (size_t)src * FIN);
#pragma unroll
        for (int q = 0; q < FIN / 4; ++q) {
            float4 v = xv[q];
            a[4 * q + 0] += v.x;
            a[4 * q + 1] += v.y;
            a[4 * q + 2] += v.z;
            a[4 * q + 3] += v.w;
        }
    }
    float ic = 1.0f / fmaxf((float)(s1 - s0), 1.0f);
#pragma unroll
    for (int i = 0; i < FIN; ++i) a[i] *= ic;

    float xr[FIN];
    {
        const float4* xv = (const float4*)(x + (size_t)n * FIN);
#pragma unroll
        for (int q = 0; q < FIN / 4; ++q) {
            float4 v = xv[q];
            xr[4 * q + 0] = v.x;
            xr[4 * q + 1] = v.y;
            xr[4 * q + 2] = v.z;
            xr[4 * q + 3] = v.w;
        }
    }

    float sq = 0.0f, g0 = 0.0f, g1 = 0.0f, r0 = 0.0f, r1 = 0.0f;
    for (int j = 0; j < HID; ++j) {
        const float4* wl = (const float4*)(W1l + (size_t)j * FIN);
        const float4* wr = (const float4*)(W1r + (size_t)j * FIN);
        float o0 = 0.0f, o1 = 0.0f, o2 = 0.0f, o3 = 0.0f;
#pragma unroll
        for (int q = 0; q < FIN / 4; ++q) {
            float4 l = wl[q];
            float4 w = wr[q];
            o0 += a[4 * q + 0] * l.x + xr[4 * q + 0] * w.x;
            o1 += a[4 * q + 1] * l.y + xr[4 * q + 1] * w.y;
            o2 += a[4 * q + 2] * l.z + xr[4 * q + 2] * w.z;
            o3 += a[4 * q + 3] * l.w + xr[4 * q + 3] * w.w;
        }
        float o = (o0 + o1) + (o2 + o3) + b1[j];
        sq += o * o;
        float p = fmaxf(o, 0.0f);              // relu before the shared /D
        g0 += p * W2l[j];
        g1 += p * W2l[HID + j];
        r0 += p * W2r[j];
        r1 += p * W2r[HID + j];
    }
    float inv = 1.0f / fmaxf(sqrtf(sq), FEPS);
    g[2 * (size_t)n]     = g0 * inv;
    g[2 * (size_t)n + 1] = g1 * inv;
    r[2 * (size_t)n]     = r0 * inv;
    r[2 * (size_t)n + 1] = r1 * inv;
}

// ---------------------------------------------------------------------------
// Kernel 5: layer-2 mean via CSR gather of g, +b2, +lin_r, L2-normalize,
// log_softmax over 2 classes, fp32 out.
// ---------------------------------------------------------------------------
__global__ __launch_bounds__(256) void finalize_kernel(
    const int* __restrict__ off, const int* __restrict__ col,
    const float* __restrict__ g, const float* __restrict__ r,
    const float* __restrict__ b2,
    float* __restrict__ out)
{
    int n = blockIdx.x * 256 + threadIdx.x;
    if (n >= NN) return;
    int s0 = off[n], s1 = off[n + 1];
    float z0 = 0.0f, z1 = 0.0f;
    for (int i = s0; i < s1; ++i) {
        int src = clampN(col[i]);
        z0 += g[2 * (size_t)src];
        z1 += g[2 * (size_t)src + 1];
    }
    float ic = 1.0f / fmaxf((float)(s1 - s0), 1.0f);
    z0 = z0 * ic + b2[0] + r[2 * (size_t)n];
    z1 = z1 * ic + b2[1] + r[2 * (size_t)n + 1];
    float d = 1.0f / fmaxf(sqrtf(z0 * z0 + z1 * z1), FEPS);
    float y0 = z0 * d, y1 = z1 * d;
    float m = fmaxf(y0, y1);
    float l = m + logf(__expf(y0 - m) + __expf(y1 - m));
    out[2 * (size_t)n]     = y0 - l;
    out[2 * (size_t)n + 1] = y1 - l;
}

// ---------------------------------------------------------------------------
extern "C" void kernel_launch(void* const* d_in, const int* in_sizes, int n_in,
                              void* d_out, int out_size, void* d_ws, size_t ws_size,
                              hipStream_t stream) {
    // setup_inputs order: x, edge_index, W1_l, b1, W1_r, W2_l, b2, W2_r
    const float* x   = (const float*)d_in[0];
    const int*   ei  = (const int*)d_in[1];
    const float* W1l = (const float*)d_in[2];
    const float* b1  = (const float*)d_in[3];
    const float* W1r = (const float*)d_in[4];
    const float* W2l = (const float*)d_in[5];
    const float* b2  = (const float*)d_in[6];
    const float* W2r = (const float*)d_in[7];

    int*   cnt  = (int*)d_ws;
    int*   cur  = cnt + NN;
    int*   off  = cur + NN;            // NN+1
    int*   col  = off + NN + 1;        // NE
    float* g    = (float*)(col + NE);  // NN*2
    float* r    = g + 2 * (size_t)NN;  // NN*2
    int*   flag = (int*)(r + 2 * (size_t)NN);

    hipMemsetAsync(cnt, 0, 2 * (size_t)NN * sizeof(int), stream);

    int eb = (NE + 255) / 256;
    detect_kernel<<<1, 64, 0, stream>>>(ei, flag);
    count_kernel<<<eb, 256, 0, stream>>>(ei, flag, cnt);
    scan_kernel<<<1, 1024, 0, stream>>>(cnt, off);
    fill_kernel<<<eb, 256, 0, stream>>>(ei, flag, off, cur, col);
    layer1_kernel<<<(NN + 255) / 256, 256, 0, stream>>>(off, col, x, W1l, W1r,
                                                        b1, W2l, W2r, g, r);
    finalize_kernel<<<(NN + 255) / 256, 256, 0, stream>>>(off, col, g, r, b2,
                                                          (float*)d_out);
}

// Round 4
// 708.892 us; speedup vs baseline: 2.6572x; 2.6572x over previous
//
#include <hip/hip_runtime.h>

// Problem constants (from reference)
#define NN  100000   // nodes
#define FIN 128      // in features
#define HID 256      // hidden
#define NE  600000   // edges
#define FEPS 1e-12f

// ---------------------------------------------------------------------------
// Workspace layout (4-byte elems, ~5.5 MB):
//   float Wt[256*256]  transposed+concat weights: Wt[k2][j], k2<128 -> W1_l
//                      (16B-aligned: placed first)
//   int   cnt[NN] | cur[NN] | off[NN+1] | col[NE]
//   float g[NN*2] | r[NN*2]
//   int   flag[1]
// ---------------------------------------------------------------------------

__device__ __forceinline__ int clampN(int v) {
    return ((unsigned)v < (unsigned)NN) ? v : 0;
}

// Detect int64 vs int32 edge_index: under little-endian int64 (< 2^31) every
// odd 32-bit word is 0; under int32 odd words are src[1],src[3],... (~never 0).
__global__ __launch_bounds__(64) void detect_kernel(
    const int* __restrict__ ei, int* __restrict__ flag)
{
    unsigned long long b = __ballot(ei[2 * threadIdx.x + 1] != 0);
    if (threadIdx.x == 0) *flag = (b == 0ULL) ? 1 : 0;
}

__device__ __forceinline__ int ld_src(const int* ei, int e, int f) {
    return f ? ei[2 * e] : ei[e];
}
__device__ __forceinline__ int ld_dst(const int* ei, int e, int f) {
    return f ? ei[2 * (NE + e)] : ei[NE + e];
}

// Kernel 1: in-degree count.
__global__ __launch_bounds__(256) void count_kernel(
    const int* __restrict__ ei, const int* __restrict__ flag,
    int* __restrict__ cnt)
{
    int e = blockIdx.x * 256 + threadIdx.x;
    if (e >= NE) return;
    int f = *flag;
    atomicAdd(cnt + clampN(ld_dst(ei, e, f)), 1);
}

// Kernel 2: exclusive prefix sum of cnt -> off (single block, 1024 threads).
__global__ __launch_bounds__(1024) void scan_kernel(
    const int* __restrict__ cnt, int* __restrict__ off)
{
    __shared__ int sm[1024];
    const int CH = (NN + 1023) / 1024;   // 98
    int t = threadIdx.x;
    int base = t * CH;
    int s = 0;
    for (int i = 0; i < CH; ++i) {
        int idx = base + i;
        if (idx < NN) s += cnt[idx];
    }
    sm[t] = s;
    __syncthreads();
    for (int d = 1; d < 1024; d <<= 1) {
        int v = (t >= d) ? sm[t - d] : 0;
        __syncthreads();
        sm[t] += v;
        __syncthreads();
    }
    int run = sm[t] - s;
    for (int i = 0; i < CH; ++i) {
        int idx = base + i;
        if (idx < NN) { off[idx] = run; run += cnt[idx]; }
    }
    if (t == 1023) off[NN] = sm[1023];
}

// Kernel 3: place src ids into CSR slots.
__global__ __launch_bounds__(256) void fill_kernel(
    const int* __restrict__ ei, const int* __restrict__ flag,
    const int* __restrict__ off, int* __restrict__ cur, int* __restrict__ col)
{
    int e = blockIdx.x * 256 + threadIdx.x;
    if (e >= NE) return;
    int f = *flag;
    int src = clampN(ld_src(ei, e, f));
    int dst = clampN(ld_dst(ei, e, f));
    int p = atomicAdd(cur + dst, 1);
    col[off[dst] + p] = src;
}

// Kernel 3.5: build Wt[k2][j] = (k2<128 ? W1l[j][k2] : W1r[j][k2-128]).
// 256 blocks x 256 threads; tiny (256 KB out), runs once per launch.
__global__ __launch_bounds__(256) void transpose_kernel(
    const float* __restrict__ W1l, const float* __restrict__ W1r,
    float* __restrict__ Wt)
{
    int k2 = blockIdx.x;
    int j  = threadIdx.x;
    float v = (k2 < FIN) ? W1l[(size_t)j * FIN + k2]
                         : W1r[(size_t)j * FIN + (k2 - FIN)];
    Wt[(size_t)k2 * HID + j] = v;
}

// ---------------------------------------------------------------------------
// Kernel 4: fused layer-1 (+ layer-2 projections), LDS-tiled GEMM.
// Block = 256 threads = 64 nodes.
// Phase A: gather/mean neighbor rows + self row into LDS, TRANSPOSED:
//          smem[k2*64 + n_loc], k2 in [0,256): first 128 = agg, rest = x-self.
//          (lane n reading smem[k2*64+lane] is 64 consecutive floats ->
//           conflict-free; 64 KB exactly = 2 blocks/CU.)
// Phase B: wave w owns j in [64w, 64w+64); o[64] accumulators in VGPRs;
//          weights Wt[k2][64w..] are wave-uniform -> s_load_dwordx16;
//          inner loop = 1 ds_read_b32 + 64 v_fmac per k2.
// Epilogue: per-wave partial (sq, g0,g1,r0,r1) -> LDS overlay (A2 dead) ->
//          threads 0..63 finish norm and write g[n], r[n].
// ---------------------------------------------------------------------------
__global__ __launch_bounds__(256, 2) void layer1_kernel(
    const int* __restrict__ off, const int* __restrict__ col,
    const float* __restrict__ x,    // [NN, FIN]
    const float* __restrict__ Wt,   // [256, HID] transposed concat weights
    const float* __restrict__ b1,   // [HID]
    const float* __restrict__ W2l,  // [2, HID]
    const float* __restrict__ W2r,  // [2, HID]
    float* __restrict__ g,          // [NN, 2]
    float* __restrict__ r)          // [NN, 2]
{
    __shared__ float smem[256 * 64];   // 64 KB; A2 then reduction overlay

    const int t     = threadIdx.x;
    const int nb    = blockIdx.x * 64;
    const int n_loc = t >> 2;          // 0..63
    const int q     = t & 3;           // feature quarter: k in [32q, 32q+32)
    const int n     = nb + n_loc;
    const bool valid = (n < NN);

    // ---- Phase A: aggregate neighbors (mean) ----
    float acc[32];
#pragma unroll
    for (int i = 0; i < 32; ++i) acc[i] = 0.0f;

    int s0 = 0, s1 = 0;
    if (valid) { s0 = off[n]; s1 = off[n + 1]; }
    for (int i = s0; i < s1; ++i) {
        int src = clampN(col[i]);
        const float4* xv = (const float4*)(x + (size_t)src * FIN + 32 * q);
#pragma unroll
        for (int u = 0; u < 8; ++u) {
            float4 v = xv[u];
            acc[4 * u + 0] += v.x;
            acc[4 * u + 1] += v.y;
            acc[4 * u + 2] += v.z;
            acc[4 * u + 3] += v.w;
        }
    }
    float ic = 1.0f / fmaxf((float)(s1 - s0), 1.0f);
#pragma unroll
    for (int i = 0; i < 32; ++i)
        smem[(32 * q + i) * 64 + n_loc] = acc[i] * ic;

    // self row -> k2 in [128+32q, 128+32q+32)
    {
        const float4* xv = (const float4*)(x + (size_t)(valid ? n : 0) * FIN + 32 * q);
#pragma unroll
        for (int u = 0; u < 8; ++u) {
            float4 v;
            if (valid) v = xv[u];
            else       v = make_float4(0.f, 0.f, 0.f, 0.f);
            smem[(FIN + 32 * q + 4 * u + 0) * 64 + n_loc] = v.x;
            smem[(FIN + 32 * q + 4 * u + 1) * 64 + n_loc] = v.y;
            smem[(FIN + 32 * q + 4 * u + 2) * 64 + n_loc] = v.z;
            smem[(FIN + 32 * q + 4 * u + 3) * 64 + n_loc] = v.w;
        }
    }
    __syncthreads();

    // ---- Phase B: o[j] for this wave's j-strip, all 64 nodes (lane=node) ----
    const int jb   = __builtin_amdgcn_readfirstlane(t >> 6);  // wave id 0..3
    const int lane = t & 63;

    float o[64];
#pragma unroll
    for (int i = 0; i < 64; ++i) o[i] = 0.0f;

#pragma unroll 1
    for (int k2 = 0; k2 < 2 * FIN; ++k2) {
        float av = smem[k2 * 64 + lane];
        const float* wrow = Wt + (size_t)k2 * HID + jb * 64;  // wave-uniform
#pragma unroll
        for (int i = 0; i < 64; ++i) o[i] += av * wrow[i];
    }

    // ---- Epilogue: bias, relu, partials ----
    float sq = 0.f, g0 = 0.f, g1 = 0.f, r0 = 0.f, r1 = 0.f;
    const float* b1w  = b1  + jb * 64;
    const float* w2la = W2l + jb * 64;
    const float* w2lb = W2l + HID + jb * 64;
    const float* w2ra = W2r + jb * 64;
    const float* w2rb = W2r + HID + jb * 64;
#pragma unroll
    for (int i = 0; i < 64; ++i) {
        float oo = o[i] + b1w[i];
        sq += oo * oo;
        float p = fmaxf(oo, 0.0f);           // relu(o/D) = relu(o)/D
        g0 += p * w2la[i];
        g1 += p * w2lb[i];
        r0 += p * w2ra[i];
        r1 += p * w2rb[i];
    }

    __syncthreads();                          // A2 now dead; reuse smem
    smem[0 * 256 + jb * 64 + lane] = sq;
    smem[1 * 256 + jb * 64 + lane] = g0;
    smem[2 * 256 + jb * 64 + lane] = g1;
    smem[3 * 256 + jb * 64 + lane] = r0;
    smem[4 * 256 + jb * 64 + lane] = r1;
    __syncthreads();

    if (t < 64) {
        int n2 = nb + t;
        float sqs = smem[t] + smem[64 + t] + smem[128 + t] + smem[192 + t];
        float G0 = smem[256 + t] + smem[256 + 64 + t] + smem[256 + 128 + t] + smem[256 + 192 + t];
        float G1 = smem[512 + t] + smem[512 + 64 + t] + smem[512 + 128 + t] + smem[512 + 192 + t];
        float R0 = smem[768 + t] + smem[768 + 64 + t] + smem[768 + 128 + t] + smem[768 + 192 + t];
        float R1 = smem[1024 + t] + smem[1024 + 64 + t] + smem[1024 + 128 + t] + smem[1024 + 192 + t];
        float inv = 1.0f / fmaxf(sqrtf(sqs), FEPS);
        if (n2 < NN) {
            g[2 * (size_t)n2]     = G0 * inv;
            g[2 * (size_t)n2 + 1] = G1 * inv;
            r[2 * (size_t)n2]     = R0 * inv;
            r[2 * (size_t)n2 + 1] = R1 * inv;
        }
    }
}

// ---------------------------------------------------------------------------
// Kernel 5: layer-2 mean via CSR gather of g, +b2, +lin_r, L2-normalize,
// log_softmax over 2 classes, fp32 out.
// ---------------------------------------------------------------------------
__global__ __launch_bounds__(256) void finalize_kernel(
    const int* __restrict__ off, const int* __restrict__ col,
    const float* __restrict__ g, const float* __restrict__ r,
    const float* __restrict__ b2,
    float* __restrict__ out)
{
    int n = blockIdx.x * 256 + threadIdx.x;
    if (n >= NN) return;
    int s0 = off[n], s1 = off[n + 1];
    float z0 = 0.0f, z1 = 0.0f;
    for (int i = s0; i < s1; ++i) {
        int src = clampN(col[i]);
        z0 += g[2 * (size_t)src];
        z1 += g[2 * (size_t)src + 1];
    }
    float ic = 1.0f / fmaxf((float)(s1 - s0), 1.0f);
    z0 = z0 * ic + b2[0] + r[2 * (size_t)n];
    z1 = z1 * ic + b2[1] + r[2 * (size_t)n + 1];
    float d = 1.0f / fmaxf(sqrtf(z0 * z0 + z1 * z1), FEPS);
    float y0 = z0 * d, y1 = z1 * d;
    float m = fmaxf(y0, y1);
    float l = m + logf(__expf(y0 - m) + __expf(y1 - m));
    out[2 * (size_t)n]     = y0 - l;
    out[2 * (size_t)n + 1] = y1 - l;
}

// ---------------------------------------------------------------------------
extern "C" void kernel_launch(void* const* d_in, const int* in_sizes, int n_in,
                              void* d_out, int out_size, void* d_ws, size_t ws_size,
                              hipStream_t stream) {
    // setup_inputs order: x, edge_index, W1_l, b1, W1_r, W2_l, b2, W2_r
    const float* x   = (const float*)d_in[0];
    const int*   ei  = (const int*)d_in[1];
    const float* W1l = (const float*)d_in[2];
    const float* b1  = (const float*)d_in[3];
    const float* W1r = (const float*)d_in[4];
    const float* W2l = (const float*)d_in[5];
    const float* b2  = (const float*)d_in[6];
    const float* W2r = (const float*)d_in[7];

    float* Wt   = (float*)d_ws;               // [256*256], 16B-aligned (first)
    int*   cnt  = (int*)(Wt + 256 * 256);
    int*   cur  = cnt + NN;
    int*   off  = cur + NN;                   // NN+1
    int*   col  = off + NN + 1;               // NE
    float* g    = (float*)(col + NE);         // NN*2
    float* r    = g + 2 * (size_t)NN;         // NN*2
    int*   flag = (int*)(r + 2 * (size_t)NN);

    hipMemsetAsync(cnt, 0, 2 * (size_t)NN * sizeof(int), stream);

    int eb = (NE + 255) / 256;
    detect_kernel<<<1, 64, 0, stream>>>(ei, flag);
    transpose_kernel<<<256, 256, 0, stream>>>(W1l, W1r, Wt);
    count_kernel<<<eb, 256, 0, stream>>>(ei, flag, cnt);
    scan_kernel<<<1, 1024, 0, stream>>>(cnt, off);
    fill_kernel<<<eb, 256, 0, stream>>>(ei, flag, off, cur, col);
    layer1_kernel<<<(NN + 63) / 64, 256, 0, stream>>>(off, col, x, Wt, b1,
                                                      W2l, W2r, g, r);
    finalize_kernel<<<(NN + 255) / 256, 256, 0, stream>>>(off, col, g, r, b2,
                                                          (float*)d_out);
}

// Round 6
// 642.010 us; speedup vs baseline: 2.9340x; 1.1042x over previous
//
#include <hip/hip_runtime.h>

// Problem constants (from reference)
#define NN  100000   // nodes
#define FIN 128      // in features
#define HID 256      // hidden
#define NE  600000   // edges
#define FEPS 1e-12f

// ---------------------------------------------------------------------------
// Workspace layout (4-byte elems, ~5.6 MB):
//   float Wt[256*256]  transposed concat weights Wt[k2][j] (16B-aligned, first)
//   int   cnt[NN] | cur[NN] | off[NN+1] | col[NE]
//   float g[NN*2] | r[NN*2]
//   int   bsum[128] | flag[1]
// NOTE (round-5 evidence): ws_size >= 33 MB on this harness; bf16 feature
// compression FAILED precision (0.465 vs 0.0327) due to 1/||z|| amplification
// in layer-2 normalize — features must stay fp32.
// ---------------------------------------------------------------------------

__device__ __forceinline__ int clampN(int v) {
    return ((unsigned)v < (unsigned)NN) ? v : 0;
}

// Detect int64 vs int32 edge_index: little-endian int64 (<2^31) has every odd
// 32-bit word zero; int32 odd words are src[1],src[3],... (~never all zero).
__global__ __launch_bounds__(64) void detect_kernel(
    const int* __restrict__ ei, int* __restrict__ flag)
{
    unsigned long long b = __ballot(ei[2 * threadIdx.x + 1] != 0);
    if (threadIdx.x == 0) *flag = (b == 0ULL) ? 1 : 0;
}

__device__ __forceinline__ int ld_src(const int* ei, int e, int f) {
    return f ? ei[2 * e] : ei[e];
}
__device__ __forceinline__ int ld_dst(const int* ei, int e, int f) {
    return f ? ei[2 * (NE + e)] : ei[NE + e];
}

// in-degree count
__global__ __launch_bounds__(256) void count_kernel(
    const int* __restrict__ ei, const int* __restrict__ flag,
    int* __restrict__ cnt)
{
    int e = blockIdx.x * 256 + threadIdx.x;
    if (e >= NE) return;
    int f = *flag;
    atomicAdd(cnt + clampN(ld_dst(ei, e, f)), 1);
}

// 3-phase parallel exclusive scan of cnt[NN] -> off[NN+1]
__global__ __launch_bounds__(1024) void scan_a_kernel(
    const int* __restrict__ cnt, int* __restrict__ off, int* __restrict__ bsum)
{
    __shared__ int sm[1024];
    int t = threadIdx.x;
    int idx = blockIdx.x * 1024 + t;
    int v = (idx < NN) ? cnt[idx] : 0;
    sm[t] = v;
    __syncthreads();
    for (int d = 1; d < 1024; d <<= 1) {
        int w = (t >= d) ? sm[t - d] : 0;
        __syncthreads();
        sm[t] += w;
        __syncthreads();
    }
    if (idx < NN) off[idx] = sm[t] - v;      // block-local exclusive
    if (t == 1023) bsum[blockIdx.x] = sm[1023];
}
__global__ __launch_bounds__(128) void scan_b_kernel(
    int* __restrict__ bsum, int* __restrict__ off, int nblocks)
{
    __shared__ int sm[128];
    int t = threadIdx.x;
    int v = (t < nblocks) ? bsum[t] : 0;
    sm[t] = v;
    __syncthreads();
    for (int d = 1; d < 128; d <<= 1) {
        int w = (t >= d) ? sm[t - d] : 0;
        __syncthreads();
        sm[t] += w;
        __syncthreads();
    }
    if (t < nblocks) bsum[t] = sm[t] - v;    // exclusive block bases
    if (t == 0) off[NN] = NE;
}
__global__ __launch_bounds__(1024) void scan_c_kernel(
    const int* __restrict__ bsum, int* __restrict__ off)
{
    int idx = blockIdx.x * 1024 + threadIdx.x;
    if (idx < NN) off[idx] += bsum[blockIdx.x];
}

// place src ids into CSR slots
__global__ __launch_bounds__(256) void fill_kernel(
    const int* __restrict__ ei, const int* __restrict__ flag,
    const int* __restrict__ off, int* __restrict__ cur, int* __restrict__ col)
{
    int e = blockIdx.x * 256 + threadIdx.x;
    if (e >= NE) return;
    int f = *flag;
    int src = clampN(ld_src(ei, e, f));
    int dst = clampN(ld_dst(ei, e, f));
    int p = atomicAdd(cur + dst, 1);
    col[off[dst] + p] = src;
}

// Wt[k2][j] = (k2<128 ? W1l[j][k2] : W1r[j][k2-128])
__global__ __launch_bounds__(256) void transpose_kernel(
    const float* __restrict__ W1l, const float* __restrict__ W1r,
    float* __restrict__ Wt)
{
    int k2 = blockIdx.x;
    int j  = threadIdx.x;
    float v = (k2 < FIN) ? W1l[(size_t)j * FIN + k2]
                         : W1r[(size_t)j * FIN + (k2 - FIN)];
    Wt[(size_t)k2 * HID + j] = v;
}

// ---------------------------------------------------------------------------
// Fused layer-1 (+ layer-2 projections), LDS-tiled fp32 GEMM. 64 nodes/block.
// LDS tile: element (k2, n) at smem_f[k2*64 + (n ^ ((k2>>1)&31))]
//   (XOR swizzle; both write and read patterns are <=2 lanes/bank => free).
// Phase A (wave-per-node): each wave aggregates its 16 nodes sequentially.
//   lane = feature pair (2 floats); node's col[] slice prefetched into lanes
//   and broadcast via __shfl so neighbor row loads (512 B coalesced) pipeline
//   with no load->load dependency. k2<128 = mean(agg), k2>=128 = self row.
// Phase B: wave w owns j-strip [64w,64w+64); o[64] in VGPRs; weight rows are
//   wave-uniform -> scalar loads; lane = node.
// Epilogue: bias/relu/L2-norm partials -> LDS overlay -> final g,r.
// ---------------------------------------------------------------------------
__global__ __launch_bounds__(256, 2) void layer1_kernel(
    const int* __restrict__ off, const int* __restrict__ col,
    const float* __restrict__ x,    // [NN, FIN] fp32
    const float* __restrict__ Wt,   // [256, HID]
    const float* __restrict__ b1,
    const float* __restrict__ W2l, const float* __restrict__ W2r,
    float* __restrict__ g, float* __restrict__ r)
{
    __shared__ float smem_f[256 * 64];   // 64 KB

    const int t  = threadIdx.x;
    const int nb = blockIdx.x * 64;
    const int w  = t >> 6;               // wave 0..3
    const int l  = t & 63;               // lane

    // ---- Phase A: wave-per-node gather/mean ----
    for (int ii = 0; ii < 16; ++ii) {
        int n_loc = 16 * w + ii;
        int n = nb + n_loc;
        bool valid = (n < NN);
        int s0 = valid ? off[n] : 0;
        int s1 = valid ? off[n + 1] : 0;   // wave-uniform

        float a0 = 0.0f, a1 = 0.0f;
        for (int base = s0; base < s1; base += 64) {
            int m = s1 - base; if (m > 64) m = 64;
            int c = (l < m) ? col[base + l] : 0;
            for (int i = 0; i < m; ++i) {
                int src = clampN(__shfl(c, i));
                const float2 v = *(const float2*)(x + (size_t)src * FIN + 2 * l);
                a0 += v.x;
                a1 += v.y;
            }
        }
        float ic = 1.0f / fmaxf((float)(s1 - s0), 1.0f);
        int nc = n_loc ^ (l & 31);         // swizzled column
        smem_f[(2 * l) * 64 + nc]     = a0 * ic;
        smem_f[(2 * l + 1) * 64 + nc] = a1 * ic;

        float2 sv = valid ? *(const float2*)(x + (size_t)n * FIN + 2 * l)
                          : make_float2(0.0f, 0.0f);
        smem_f[(FIN + 2 * l) * 64 + nc]     = sv.x;
        smem_f[(FIN + 2 * l + 1) * 64 + nc] = sv.y;
    }
    __syncthreads();

    // ---- Phase B: lane = node; wave w owns j in [64w, 64w+64) ----
    const int jb = __builtin_amdgcn_readfirstlane(w);

    float o[64];
#pragma unroll
    for (int i = 0; i < 64; ++i) o[i] = 0.0f;

#pragma unroll 1
    for (int k2 = 0; k2 < 2 * FIN; ++k2) {
        float av = smem_f[k2 * 64 + (l ^ ((k2 >> 1) & 31))];
        const float* wrow = Wt + (size_t)k2 * HID + jb * 64;  // wave-uniform
#pragma unroll
        for (int i = 0; i < 64; ++i) o[i] += av * wrow[i];
    }

    // ---- Epilogue ----
    float sq = 0.f, g0 = 0.f, g1 = 0.f, r0 = 0.f, r1 = 0.f;
    const float* b1w  = b1  + jb * 64;
    const float* w2la = W2l + jb * 64;
    const float* w2lb = W2l + HID + jb * 64;
    const float* w2ra = W2r + jb * 64;
    const float* w2rb = W2r + HID + jb * 64;
#pragma unroll
    for (int i = 0; i < 64; ++i) {
        float oo = o[i] + b1w[i];
        sq += oo * oo;
        float p = fmaxf(oo, 0.0f);           // relu(o/D) = relu(o)/D
        g0 += p * w2la[i];
        g1 += p * w2lb[i];
        r0 += p * w2ra[i];
        r1 += p * w2rb[i];
    }

    __syncthreads();                          // tile dead; reuse as overlay
    smem_f[0 * 256 + w * 64 + l] = sq;
    smem_f[1 * 256 + w * 64 + l] = g0;
    smem_f[2 * 256 + w * 64 + l] = g1;
    smem_f[3 * 256 + w * 64 + l] = r0;
    smem_f[4 * 256 + w * 64 + l] = r1;
    __syncthreads();

    if (t < 64) {
        int n2 = nb + t;
        float sqs = smem_f[t] + smem_f[64 + t] + smem_f[128 + t] + smem_f[192 + t];
        float G0 = smem_f[256 + t] + smem_f[320 + t] + smem_f[384 + t] + smem_f[448 + t];
        float G1 = smem_f[512 + t] + smem_f[576 + t] + smem_f[640 + t] + smem_f[704 + t];
        float R0 = smem_f[768 + t] + smem_f[832 + t] + smem_f[896 + t] + smem_f[960 + t];
        float R1 = smem_f[1024 + t] + smem_f[1088 + t] + smem_f[1152 + t] + smem_f[1216 + t];
        float inv = 1.0f / fmaxf(sqrtf(sqs), FEPS);
        if (n2 < NN) {
            g[2 * (size_t)n2]     = G0 * inv;
            g[2 * (size_t)n2 + 1] = G1 * inv;
            r[2 * (size_t)n2]     = R0 * inv;
            r[2 * (size_t)n2 + 1] = R1 * inv;
        }
    }
}

// layer-2 mean via CSR gather of g, +b2, +lin_r, L2-normalize, log_softmax
__global__ __launch_bounds__(256) void finalize_kernel(
    const int* __restrict__ off, const int* __restrict__ col,
    const float* __restrict__ g, const float* __restrict__ r,
    const float* __restrict__ b2,
    float* __restrict__ out)
{
    int n = blockIdx.x * 256 + threadIdx.x;
    if (n >= NN) return;
    int s0 = off[n], s1 = off[n + 1];
    float z0 = 0.0f, z1 = 0.0f;
    for (int i = s0; i < s1; ++i) {
        int src = clampN(col[i]);
        z0 += g[2 * (size_t)src];
        z1 += g[2 * (size_t)src + 1];
    }
    float ic = 1.0f / fmaxf((float)(s1 - s0), 1.0f);
    z0 = z0 * ic + b2[0] + r[2 * (size_t)n];
    z1 = z1 * ic + b2[1] + r[2 * (size_t)n + 1];
    float d = 1.0f / fmaxf(sqrtf(z0 * z0 + z1 * z1), FEPS);
    float y0 = z0 * d, y1 = z1 * d;
    float m = fmaxf(y0, y1);
    float l = m + logf(__expf(y0 - m) + __expf(y1 - m));
    out[2 * (size_t)n]     = y0 - l;
    out[2 * (size_t)n + 1] = y1 - l;
}

// ---------------------------------------------------------------------------
extern "C" void kernel_launch(void* const* d_in, const int* in_sizes, int n_in,
                              void* d_out, int out_size, void* d_ws, size_t ws_size,
                              hipStream_t stream) {
    // setup_inputs order: x, edge_index, W1_l, b1, W1_r, W2_l, b2, W2_r
    const float* x   = (const float*)d_in[0];
    const int*   ei  = (const int*)d_in[1];
    const float* W1l = (const float*)d_in[2];
    const float* b1  = (const float*)d_in[3];
    const float* W1r = (const float*)d_in[4];
    const float* W2l = (const float*)d_in[5];
    const float* b2  = (const float*)d_in[6];
    const float* W2r = (const float*)d_in[7];

    const int nsb = (NN + 1023) / 1024;  // 98 scan blocks

    float* Wt   = (float*)d_ws;                  // [256*256]
    int*   cnt  = (int*)(Wt + 256 * 256);
    int*   cur  = cnt + NN;
    int*   off  = cur + NN;                      // NN+1
    int*   col  = off + NN + 1;                  // NE
    float* g    = (float*)(col + NE);            // NN*2
    float* r    = g + 2 * (size_t)NN;            // NN*2
    int*   bsum = (int*)(r + 2 * (size_t)NN);    // 128
    int*   flag = bsum + 128;

    hipMemsetAsync(cnt, 0, 2 * (size_t)NN * sizeof(int), stream);

    int eb = (NE + 255) / 256;
    detect_kernel<<<1, 64, 0, stream>>>(ei, flag);
    transpose_kernel<<<256, 256, 0, stream>>>(W1l, W1r, Wt);
    count_kernel<<<eb, 256, 0, stream>>>(ei, flag, cnt);
    scan_a_kernel<<<nsb, 1024, 0, stream>>>(cnt, off, bsum);
    scan_b_kernel<<<1, 128, 0, stream>>>(bsum, off, nsb);
    scan_c_kernel<<<nsb, 1024, 0, stream>>>(bsum, off);
    fill_kernel<<<eb, 256, 0, stream>>>(ei, flag, off, cur, col);
    layer1_kernel<<<(NN + 63) / 64, 256, 0, stream>>>(off, col, x, Wt, b1,
                                                      W2l, W2r, g, r);
    finalize_kernel<<<(NN + 255) / 256, 256, 0, stream>>>(off, col, g, r, b2,
                                                          (float*)d_out);
}

// Round 7
// 452.624 us; speedup vs baseline: 4.1616x; 1.4184x over previous
//
#include <hip/hip_runtime.h>

// Problem constants (from reference)
#define NN  100000   // nodes
#define FIN 128      // in features
#define HID 256      // hidden
#define NE  600000   // edges
#define FEPS 1e-12f

// ---------------------------------------------------------------------------
// Workspace layout (4-byte elems, ~5.6 MB):
//   float Wt[256*256]  transposed concat weights Wt[k2][j] (16B-aligned, first)
//   int   cnt[NN] | cur[NN] | off[NN+1] | col[NE]
//   float g[NN*2] | r[NN*2]
//   int   bsum[128] | flag[1]
// Evidence log:
//  - R5: ws_size >= 33 MB; bf16 features FAIL precision (1/||z|| amplification)
//  - R6: wave-per-node gather REGRESSED (1 load in flight/wave). Use
//    thread-parallel gather with unrolled independent loads.
// ---------------------------------------------------------------------------

__device__ __forceinline__ int clampN(int v) {
    return ((unsigned)v < (unsigned)NN) ? v : 0;
}

// Detect int64 vs int32 edge_index: little-endian int64 (<2^31) has every odd
// 32-bit word zero; int32 odd words are src[1],src[3],... (~never all zero).
__global__ __launch_bounds__(64) void detect_kernel(
    const int* __restrict__ ei, int* __restrict__ flag)
{
    unsigned long long b = __ballot(ei[2 * threadIdx.x + 1] != 0);
    if (threadIdx.x == 0) *flag = (b == 0ULL) ? 1 : 0;
}

__device__ __forceinline__ int ld_src(const int* ei, int e, int f) {
    return f ? ei[2 * e] : ei[e];
}
__device__ __forceinline__ int ld_dst(const int* ei, int e, int f) {
    return f ? ei[2 * (NE + e)] : ei[NE + e];
}

// in-degree count
__global__ __launch_bounds__(256) void count_kernel(
    const int* __restrict__ ei, const int* __restrict__ flag,
    int* __restrict__ cnt)
{
    int e = blockIdx.x * 256 + threadIdx.x;
    if (e >= NE) return;
    int f = *flag;
    atomicAdd(cnt + clampN(ld_dst(ei, e, f)), 1);
}

// 3-phase parallel exclusive scan of cnt[NN] -> off[NN+1]
__global__ __launch_bounds__(1024) void scan_a_kernel(
    const int* __restrict__ cnt, int* __restrict__ off, int* __restrict__ bsum)
{
    __shared__ int sm[1024];
    int t = threadIdx.x;
    int idx = blockIdx.x * 1024 + t;
    int v = (idx < NN) ? cnt[idx] : 0;
    sm[t] = v;
    __syncthreads();
    for (int d = 1; d < 1024; d <<= 1) {
        int w = (t >= d) ? sm[t - d] : 0;
        __syncthreads();
        sm[t] += w;
        __syncthreads();
    }
    if (idx < NN) off[idx] = sm[t] - v;      // block-local exclusive
    if (t == 1023) bsum[blockIdx.x] = sm[1023];
}
__global__ __launch_bounds__(128) void scan_b_kernel(
    int* __restrict__ bsum, int* __restrict__ off, int nblocks)
{
    __shared__ int sm[128];
    int t = threadIdx.x;
    int v = (t < nblocks) ? bsum[t] : 0;
    sm[t] = v;
    __syncthreads();
    for (int d = 1; d < 128; d <<= 1) {
        int w = (t >= d) ? sm[t - d] : 0;
        __syncthreads();
        sm[t] += w;
        __syncthreads();
    }
    if (t < nblocks) bsum[t] = sm[t] - v;    // exclusive block bases
    if (t == 0) off[NN] = NE;
}
__global__ __launch_bounds__(1024) void scan_c_kernel(
    const int* __restrict__ bsum, int* __restrict__ off)
{
    int idx = blockIdx.x * 1024 + threadIdx.x;
    if (idx < NN) off[idx] += bsum[blockIdx.x];
}

// place src ids into CSR slots
__global__ __launch_bounds__(256) void fill_kernel(
    const int* __restrict__ ei, const int* __restrict__ flag,
    const int* __restrict__ off, int* __restrict__ cur, int* __restrict__ col)
{
    int e = blockIdx.x * 256 + threadIdx.x;
    if (e >= NE) return;
    int f = *flag;
    int src = clampN(ld_src(ei, e, f));
    int dst = clampN(ld_dst(ei, e, f));
    int p = atomicAdd(cur + dst, 1);
    col[off[dst] + p] = src;
}

// Wt[k2][j] = (k2<128 ? W1l[j][k2] : W1r[j][k2-128])
__global__ __launch_bounds__(256) void transpose_kernel(
    const float* __restrict__ W1l, const float* __restrict__ W1r,
    float* __restrict__ Wt)
{
    int k2 = blockIdx.x;
    int j  = threadIdx.x;
    float v = (k2 < FIN) ? W1l[(size_t)j * FIN + k2]
                         : W1r[(size_t)j * FIN + (k2 - FIN)];
    Wt[(size_t)k2 * HID + j] = v;
}

// ---------------------------------------------------------------------------
// Fused layer-1 (+ layer-2 projections), LDS-tiled fp32 GEMM.
// 512 threads/block, 64 nodes/block, 64 KB tile -> 2 blocks/CU = 16 waves/CU.
// LDS tile: element (f, n) at smem_f[f*64 + (n ^ (f&31))]
//   phase-B reads: <=2 lanes/bank (free); phase-A stores ~4-way (negligible).
// Phase A: 8 threads/node, 16 contiguous features each; neighbor loop
//   unrolled x2 with independent accumulator sets -> 8 outstanding float4
//   loads per thread (R6 lesson: maximize per-thread MLP).
// Phase B: 8 waves; wave w owns j-strip [32w, 32w+32); o[32] in VGPRs;
//   weight rows wave-uniform -> scalar loads; lane = node.
// Epilogue: bias/relu/L2-norm partials -> LDS overlay -> final g,r.
// ---------------------------------------------------------------------------
__global__ __launch_bounds__(512, 4) void layer1_kernel(
    const int* __restrict__ off, const int* __restrict__ col,
    const float* __restrict__ x,    // [NN, FIN] fp32
    const float* __restrict__ Wt,   // [256, HID]
    const float* __restrict__ b1,
    const float* __restrict__ W2l, const float* __restrict__ W2r,
    float* __restrict__ g, float* __restrict__ r)
{
    __shared__ float smem_f[256 * 64];   // 64 KB

    const int t  = threadIdx.x;          // 0..511
    const int nb = blockIdx.x * 64;

    // ---- Phase A: thread-parallel gather/mean ----
    {
        const int n_loc = t >> 3;        // 0..63
        const int ft    = t & 7;         // feature group (16 floats)
        const int fbase = ft * 16;
        const int n     = nb + n_loc;
        const bool valid = (n < NN);

        float a0[16], a1[16];
#pragma unroll
        for (int i = 0; i < 16; ++i) { a0[i] = 0.0f; a1[i] = 0.0f; }

        int s0 = 0, s1 = 0;
        if (valid) { s0 = off[n]; s1 = off[n + 1]; }

        int i = s0;
        for (; i + 1 < s1; i += 2) {     // 2 neighbors in flight
            int c0 = clampN(col[i]);
            int c1 = clampN(col[i + 1]);
            const float4* p0 = (const float4*)(x + (size_t)c0 * FIN + fbase);
            const float4* p1 = (const float4*)(x + (size_t)c1 * FIN + fbase);
            float4 v00 = p0[0], v01 = p0[1], v02 = p0[2], v03 = p0[3];
            float4 v10 = p1[0], v11 = p1[1], v12 = p1[2], v13 = p1[3];
            a0[0] += v00.x;  a0[1] += v00.y;  a0[2] += v00.z;  a0[3] += v00.w;
            a0[4] += v01.x;  a0[5] += v01.y;  a0[6] += v01.z;  a0[7] += v01.w;
            a0[8] += v02.x;  a0[9] += v02.y;  a0[10] += v02.z; a0[11] += v02.w;
            a0[12] += v03.x; a0[13] += v03.y; a0[14] += v03.z; a0[15] += v03.w;
            a1[0] += v10.x;  a1[1] += v10.y;  a1[2] += v10.z;  a1[3] += v10.w;
            a1[4] += v11.x;  a1[5] += v11.y;  a1[6] += v11.z;  a1[7] += v11.w;
            a1[8] += v12.x;  a1[9] += v12.y;  a1[10] += v12.z; a1[11] += v12.w;
            a1[12] += v13.x; a1[13] += v13.y; a1[14] += v13.z; a1[15] += v13.w;
        }
        if (i < s1) {
            int c0 = clampN(col[i]);
            const float4* p0 = (const float4*)(x + (size_t)c0 * FIN + fbase);
            float4 v00 = p0[0], v01 = p0[1], v02 = p0[2], v03 = p0[3];
            a0[0] += v00.x;  a0[1] += v00.y;  a0[2] += v00.z;  a0[3] += v00.w;
            a0[4] += v01.x;  a0[5] += v01.y;  a0[6] += v01.z;  a0[7] += v01.w;
            a0[8] += v02.x;  a0[9] += v02.y;  a0[10] += v02.z; a0[11] += v02.w;
            a0[12] += v03.x; a0[13] += v03.y; a0[14] += v03.z; a0[15] += v03.w;
        }
        float ic = 1.0f / fmaxf((float)(s1 - s0), 1.0f);
#pragma unroll
        for (int k = 0; k < 16; ++k) {
            int f = fbase + k;
            smem_f[f * 64 + ((n_loc ^ f) & 31 | (n_loc & 32))] = (a0[k] + a1[k]) * ic;
        }
        // self row
        const float4* sp = (const float4*)(x + (size_t)(valid ? n : 0) * FIN + fbase);
        float4 s[4];
#pragma unroll
        for (int u = 0; u < 4; ++u)
            s[u] = valid ? sp[u] : make_float4(0.f, 0.f, 0.f, 0.f);
#pragma unroll
        for (int k = 0; k < 16; ++k) {
            int f = FIN + fbase + k;
            float v = ((const float*)s)[k];
            smem_f[f * 64 + ((n_loc ^ f) & 31 | (n_loc & 32))] = v;
        }
    }
    __syncthreads();

    // ---- Phase B: 8 waves, wave w owns j in [32w, 32w+32); lane = node ----
    const int w  = __builtin_amdgcn_readfirstlane(t >> 6);  // 0..7
    const int l  = t & 63;
    const int jb = w * 32;

    float o[32];
#pragma unroll
    for (int i = 0; i < 32; ++i) o[i] = 0.0f;

#pragma unroll 1
    for (int k2 = 0; k2 < 2 * FIN; ++k2) {
        float av = smem_f[k2 * 64 + ((l ^ k2) & 31 | (l & 32))];
        const float* wrow = Wt + (size_t)k2 * HID + jb;   // wave-uniform
#pragma unroll
        for (int i = 0; i < 32; ++i) o[i] += av * wrow[i];
    }

    // ---- Epilogue: bias, relu, partials over this wave's 32 j's ----
    float sq = 0.f, g0 = 0.f, g1 = 0.f, r0 = 0.f, r1 = 0.f;
    const float* b1w  = b1  + jb;
    const float* w2la = W2l + jb;
    const float* w2lb = W2l + HID + jb;
    const float* w2ra = W2r + jb;
    const float* w2rb = W2r + HID + jb;
#pragma unroll
    for (int i = 0; i < 32; ++i) {
        float oo = o[i] + b1w[i];
        sq += oo * oo;
        float p = fmaxf(oo, 0.0f);           // relu(o/D) = relu(o)/D
        g0 += p * w2la[i];
        g1 += p * w2lb[i];
        r0 += p * w2ra[i];
        r1 += p * w2rb[i];
    }

    __syncthreads();                          // tile dead; reuse as overlay
    smem_f[0 * 512 + t] = sq;
    smem_f[1 * 512 + t] = g0;
    smem_f[2 * 512 + t] = g1;
    smem_f[3 * 512 + t] = r0;
    smem_f[4 * 512 + t] = r1;
    __syncthreads();

    if (t < 64) {
        int n2 = nb + t;
        float sqs = 0.f, G0 = 0.f, G1 = 0.f, R0 = 0.f, R1 = 0.f;
#pragma unroll
        for (int ww = 0; ww < 8; ++ww) {
            sqs += smem_f[0 * 512 + ww * 64 + t];
            G0  += smem_f[1 * 512 + ww * 64 + t];
            G1  += smem_f[2 * 512 + ww * 64 + t];
            R0  += smem_f[3 * 512 + ww * 64 + t];
            R1  += smem_f[4 * 512 + ww * 64 + t];
        }
        float inv = 1.0f / fmaxf(sqrtf(sqs), FEPS);
        if (n2 < NN) {
            g[2 * (size_t)n2]     = G0 * inv;
            g[2 * (size_t)n2 + 1] = G1 * inv;
            r[2 * (size_t)n2]     = R0 * inv;
            r[2 * (size_t)n2 + 1] = R1 * inv;
        }
    }
}

// layer-2 mean via CSR gather of g, +b2, +lin_r, L2-normalize, log_softmax
__global__ __launch_bounds__(256) void finalize_kernel(
    const int* __restrict__ off, const int* __restrict__ col,
    const float* __restrict__ g, const float* __restrict__ r,
    const float* __restrict__ b2,
    float* __restrict__ out)
{
    int n = blockIdx.x * 256 + threadIdx.x;
    if (n >= NN) return;
    int s0 = off[n], s1 = off[n + 1];
    float z0 = 0.0f, z1 = 0.0f, y0b = 0.0f, y1b = 0.0f;
    int i = s0;
    for (; i + 1 < s1; i += 2) {             // 2 gathers in flight
        int sa = clampN(col[i]);
        int sb = clampN(col[i + 1]);
        float2 va = *(const float2*)(g + 2 * (size_t)sa);
        float2 vb = *(const float2*)(g + 2 * (size_t)sb);
        z0 += va.x; z1 += va.y;
        y0b += vb.x; y1b += vb.y;
    }
    if (i < s1) {
        int sa = clampN(col[i]);
        float2 va = *(const float2*)(g + 2 * (size_t)sa);
        z0 += va.x; z1 += va.y;
    }
    z0 += y0b; z1 += y1b;
    float ic = 1.0f / fmaxf((float)(s1 - s0), 1.0f);
    z0 = z0 * ic + b2[0] + r[2 * (size_t)n];
    z1 = z1 * ic + b2[1] + r[2 * (size_t)n + 1];
    float d = 1.0f / fmaxf(sqrtf(z0 * z0 + z1 * z1), FEPS);
    float y0 = z0 * d, y1 = z1 * d;
    float m = fmaxf(y0, y1);
    float l = m + logf(__expf(y0 - m) + __expf(y1 - m));
    out[2 * (size_t)n]     = y0 - l;
    out[2 * (size_t)n + 1] = y1 - l;
}

// ---------------------------------------------------------------------------
extern "C" void kernel_launch(void* const* d_in, const int* in_sizes, int n_in,
                              void* d_out, int out_size, void* d_ws, size_t ws_size,
                              hipStream_t stream) {
    // setup_inputs order: x, edge_index, W1_l, b1, W1_r, W2_l, b2, W2_r
    const float* x   = (const float*)d_in[0];
    const int*   ei  = (const int*)d_in[1];
    const float* W1l = (const float*)d_in[2];
    const float* b1  = (const float*)d_in[3];
    const float* W1r = (const float*)d_in[4];
    const float* W2l = (const float*)d_in[5];
    const float* b2  = (const float*)d_in[6];
    const float* W2r = (const float*)d_in[7];

    const int nsb = (NN + 1023) / 1024;  // 98 scan blocks

    float* Wt   = (float*)d_ws;                  // [256*256]
    int*   cnt  = (int*)(Wt + 256 * 256);
    int*   cur  = cnt + NN;
    int*   off  = cur + NN;                      // NN+1
    int*   col  = off + NN + 1;                  // NE
    float* g    = (float*)(col + NE);            // NN*2
    float* r    = g + 2 * (size_t)NN;            // NN*2
    int*   bsum = (int*)(r + 2 * (size_t)NN);    // 128
    int*   flag = bsum + 128;

    hipMemsetAsync(cnt, 0, 2 * (size_t)NN * sizeof(int), stream);

    int eb = (NE + 255) / 256;
    detect_kernel<<<1, 64, 0, stream>>>(ei, flag);
    transpose_kernel<<<256, 256, 0, stream>>>(W1l, W1r, Wt);
    count_kernel<<<eb, 256, 0, stream>>>(ei, flag, cnt);
    scan_a_kernel<<<nsb, 1024, 0, stream>>>(cnt, off, bsum);
    scan_b_kernel<<<1, 128, 0, stream>>>(bsum, off, nsb);
    scan_c_kernel<<<nsb, 1024, 0, stream>>>(bsum, off);
    fill_kernel<<<eb, 256, 0, stream>>>(ei, flag, off, cur, col);
    layer1_kernel<<<(NN + 63) / 64, 512, 0, stream>>>(off, col, x, Wt, b1,
                                                      W2l, W2r, g, r);
    finalize_kernel<<<(NN + 255) / 256, 256, 0, stream>>>(off, col, g, r, b2,
                                                          (float*)d_out);
}

// Round 8
// 436.588 us; speedup vs baseline: 4.3145x; 1.0367x over previous
//
#include <hip/hip_runtime.h>

// Problem constants (from reference)
#define NN  100000   // nodes
#define FIN 128      // in features
#define HID 256      // hidden
#define NE  600000   // edges
#define FEPS 1e-12f

// ---------------------------------------------------------------------------
// Workspace layout (4-byte elems, ~5.6 MB):
//   float Wt[256*256] | int cnt[NN] | cur[NN] | off[NN+1] | col[NE]
//   float g[NN*2] | r[NN*2] | int bsum[128] | flag[1]
// Evidence log:
//  - R5: ws_size >= 33 MB; bf16 features FAIL precision (1/||z|| amplification
//    through the layer-2 L2-normalize) — features must stay fp32.
//  - R6: wave-per-node gather REGRESSED (too few loads in flight per wave).
//  - R7: 16 waves/CU + 8-deep per-thread MLP: layer1 507->309 us. Still
//    latency-bound (VALUBusy 38%, BW 7%) -> push occupancy to 32 waves/CU.
// ---------------------------------------------------------------------------

__device__ __forceinline__ int clampN(int v) {
    return ((unsigned)v < (unsigned)NN) ? v : 0;
}
__device__ __forceinline__ int ld_src(const int* ei, int e, int f) {
    return f ? ei[2 * e] : ei[e];
}
__device__ __forceinline__ int ld_dst(const int* ei, int e, int f) {
    return f ? ei[2 * (NE + e)] : ei[NE + e];
}

// ---------------------------------------------------------------------------
// Setup (fused): block 0 = int64/int32 detect; blocks 1..256 = weight
// transpose Wt[k2][j]; all blocks stride-zero cnt+cur.
// ---------------------------------------------------------------------------
__global__ __launch_bounds__(256) void setup_kernel(
    const int* __restrict__ ei,
    const float* __restrict__ W1l, const float* __restrict__ W1r,
    float* __restrict__ Wt, int* __restrict__ cnt2 /* cnt|cur, 2*NN */,
    int* __restrict__ flag)
{
    int b = blockIdx.x;
    int t = threadIdx.x;
    if (b == 0) {
        if (t < 64) {
            // int64 little-endian (<2^31): every odd 32-bit word is 0.
            unsigned long long bal = __ballot(t < 64 ? (ei[2 * t + 1] != 0) : false);
            if (t == 0) *flag = (bal == 0ULL) ? 1 : 0;
        }
    } else {
        int k2 = b - 1;
        float v = (k2 < FIN) ? W1l[(size_t)t * FIN + k2]
                             : W1r[(size_t)t * FIN + (k2 - FIN)];
        Wt[(size_t)k2 * HID + t] = v;
    }
    for (int idx = b * 256 + t; idx < 2 * NN; idx += 257 * 256)
        cnt2[idx] = 0;
}

// in-degree count
__global__ __launch_bounds__(256) void count_kernel(
    const int* __restrict__ ei, const int* __restrict__ flag,
    int* __restrict__ cnt)
{
    int e = blockIdx.x * 256 + threadIdx.x;
    if (e >= NE) return;
    int f = *flag;
    atomicAdd(cnt + clampN(ld_dst(ei, e, f)), 1);
}

// 3-phase parallel exclusive scan of cnt[NN] -> off[NN+1]
__global__ __launch_bounds__(1024) void scan_a_kernel(
    const int* __restrict__ cnt, int* __restrict__ off, int* __restrict__ bsum)
{
    __shared__ int sm[1024];
    int t = threadIdx.x;
    int idx = blockIdx.x * 1024 + t;
    int v = (idx < NN) ? cnt[idx] : 0;
    sm[t] = v;
    __syncthreads();
    for (int d = 1; d < 1024; d <<= 1) {
        int w = (t >= d) ? sm[t - d] : 0;
        __syncthreads();
        sm[t] += w;
        __syncthreads();
    }
    if (idx < NN) off[idx] = sm[t] - v;
    if (t == 1023) bsum[blockIdx.x] = sm[1023];
}
__global__ __launch_bounds__(128) void scan_b_kernel(
    int* __restrict__ bsum, int* __restrict__ off, int nblocks)
{
    __shared__ int sm[128];
    int t = threadIdx.x;
    int v = (t < nblocks) ? bsum[t] : 0;
    sm[t] = v;
    __syncthreads();
    for (int d = 1; d < 128; d <<= 1) {
        int w = (t >= d) ? sm[t - d] : 0;
        __syncthreads();
        sm[t] += w;
        __syncthreads();
    }
    if (t < nblocks) bsum[t] = sm[t] - v;
    if (t == 0) off[NN] = NE;
}
__global__ __launch_bounds__(1024) void scan_c_kernel(
    const int* __restrict__ bsum, int* __restrict__ off)
{
    int idx = blockIdx.x * 1024 + threadIdx.x;
    if (idx < NN) off[idx] += bsum[blockIdx.x];
}

// place src ids into CSR slots
__global__ __launch_bounds__(256) void fill_kernel(
    const int* __restrict__ ei, const int* __restrict__ flag,
    const int* __restrict__ off, int* __restrict__ cur, int* __restrict__ col)
{
    int e = blockIdx.x * 256 + threadIdx.x;
    if (e >= NE) return;
    int f = *flag;
    int src = clampN(ld_src(ei, e, f));
    int dst = clampN(ld_dst(ei, e, f));
    int p = atomicAdd(cur + dst, 1);
    col[off[dst] + p] = src;
}

// ---------------------------------------------------------------------------
// Fused layer-1 (+ layer-2 projections), LDS-tiled fp32 GEMM.
// 1024 threads/block, 64 nodes/block, 64 KB tile -> 2 blocks/CU = 32 waves/CU.
// LDS tile: element (f, n) at smem_f[f*64 + (n ^ ((f>>3)&31))]
//   phase-B reads 2-way (free, m136); phase-A stores ~4-way (negligible).
// Phase A: 16 threads/node, 8 contiguous features each; neighbor loop
//   unrolled x4 -> 8 independent float4 loads in flight per thread.
// Phase B: 16 waves; wave w owns j-strip [16w, 16w+16); o[16] in VGPRs;
//   weight rows wave-uniform -> s_load_dwordx16; lane = node.
// Epilogue: bias/relu/L2-norm partials -> LDS overlay -> final g,r.
// __launch_bounds__(1024,8) caps VGPR at 64 so 2 blocks/CU actually fit.
// ---------------------------------------------------------------------------
__global__ __launch_bounds__(1024, 8) void layer1_kernel(
    const int* __restrict__ off, const int* __restrict__ col,
    const float* __restrict__ x,    // [NN, FIN] fp32
    const float* __restrict__ Wt,   // [256, HID]
    const float* __restrict__ b1,
    const float* __restrict__ W2l, const float* __restrict__ W2r,
    float* __restrict__ g, float* __restrict__ r)
{
    __shared__ float smem_f[256 * 64];   // 64 KB

    const int t  = threadIdx.x;          // 0..1023
    const int nb = blockIdx.x * 64;

    // ---- Phase A: thread-parallel gather/mean ----
    {
        const int n_loc = t >> 4;        // 0..63
        const int ft    = t & 15;        // feature group (8 floats)
        const int fbase = ft * 8;
        const int n     = nb + n_loc;
        const bool valid = (n < NN);

        float a[8];
#pragma unroll
        for (int i = 0; i < 8; ++i) a[i] = 0.0f;

        int s0 = 0, s1 = 0;
        if (valid) { s0 = off[n]; s1 = off[n + 1]; }

        int i = s0;
        for (; i + 3 < s1; i += 4) {     // 4 neighbors = 8 float4s in flight
            int c0 = clampN(col[i]);
            int c1 = clampN(col[i + 1]);
            int c2 = clampN(col[i + 2]);
            int c3 = clampN(col[i + 3]);
            const float4* p0 = (const float4*)(x + (size_t)c0 * FIN + fbase);
            const float4* p1 = (const float4*)(x + (size_t)c1 * FIN + fbase);
            const float4* p2 = (const float4*)(x + (size_t)c2 * FIN + fbase);
            const float4* p3 = (const float4*)(x + (size_t)c3 * FIN + fbase);
            float4 v00 = p0[0], v01 = p0[1];
            float4 v10 = p1[0], v11 = p1[1];
            float4 v20 = p2[0], v21 = p2[1];
            float4 v30 = p3[0], v31 = p3[1];
            a[0] += v00.x + v10.x + v20.x + v30.x;
            a[1] += v00.y + v10.y + v20.y + v30.y;
            a[2] += v00.z + v10.z + v20.z + v30.z;
            a[3] += v00.w + v10.w + v20.w + v30.w;
            a[4] += v01.x + v11.x + v21.x + v31.x;
            a[5] += v01.y + v11.y + v21.y + v31.y;
            a[6] += v01.z + v11.z + v21.z + v31.z;
            a[7] += v01.w + v11.w + v21.w + v31.w;
        }
        for (; i < s1; ++i) {
            int c0 = clampN(col[i]);
            const float4* p0 = (const float4*)(x + (size_t)c0 * FIN + fbase);
            float4 v00 = p0[0], v01 = p0[1];
            a[0] += v00.x; a[1] += v00.y; a[2] += v00.z; a[3] += v00.w;
            a[4] += v01.x; a[5] += v01.y; a[6] += v01.z; a[7] += v01.w;
        }
        float ic = 1.0f / fmaxf((float)(s1 - s0), 1.0f);
#pragma unroll
        for (int k = 0; k < 8; ++k) {
            int f = fbase + k;
            smem_f[f * 64 + (n_loc ^ ((f >> 3) & 31))] = a[k] * ic;
        }
        // self row
        const float4* sp = (const float4*)(x + (size_t)(valid ? n : 0) * FIN + fbase);
        float4 s0v = valid ? sp[0] : make_float4(0.f, 0.f, 0.f, 0.f);
        float4 s1v = valid ? sp[1] : make_float4(0.f, 0.f, 0.f, 0.f);
        float sv[8] = {s0v.x, s0v.y, s0v.z, s0v.w, s1v.x, s1v.y, s1v.z, s1v.w};
#pragma unroll
        for (int k = 0; k < 8; ++k) {
            int f = FIN + fbase + k;
            smem_f[f * 64 + (n_loc ^ ((f >> 3) & 31))] = sv[k];
        }
    }
    __syncthreads();

    // ---- Phase B: 16 waves, wave w owns j in [16w, 16w+16); lane = node ----
    const int w  = __builtin_amdgcn_readfirstlane(t >> 6);  // 0..15
    const int l  = t & 63;
    const int jb = w * 16;

    float o[16];
#pragma unroll
    for (int i = 0; i < 16; ++i) o[i] = 0.0f;

#pragma unroll 1
    for (int k2 = 0; k2 < 2 * FIN; ++k2) {
        float av = smem_f[k2 * 64 + (l ^ ((k2 >> 3) & 31))];
        const float* wrow = Wt + (size_t)k2 * HID + jb;   // wave-uniform
#pragma unroll
        for (int i = 0; i < 16; ++i) o[i] += av * wrow[i];
    }

    // ---- Epilogue: bias, relu, partials over this wave's 16 j's ----
    float sq = 0.f, g0 = 0.f, g1 = 0.f, r0 = 0.f, r1 = 0.f;
    const float* b1w  = b1  + jb;
    const float* w2la = W2l + jb;
    const float* w2lb = W2l + HID + jb;
    const float* w2ra = W2r + jb;
    const float* w2rb = W2r + HID + jb;
#pragma unroll
    for (int i = 0; i < 16; ++i) {
        float oo = o[i] + b1w[i];
        sq += oo * oo;
        float p = fmaxf(oo, 0.0f);           // relu(o/D) = relu(o)/D
        g0 += p * w2la[i];
        g1 += p * w2lb[i];
        r0 += p * w2ra[i];
        r1 += p * w2rb[i];
    }

    __syncthreads();                          // tile dead; reuse as overlay
    smem_f[0 * 1024 + t] = sq;
    smem_f[1 * 1024 + t] = g0;
    smem_f[2 * 1024 + t] = g1;
    smem_f[3 * 1024 + t] = r0;
    smem_f[4 * 1024 + t] = r1;
    __syncthreads();

    if (t < 64) {
        int n2 = nb + t;
        float sqs = 0.f, G0 = 0.f, G1 = 0.f, R0 = 0.f, R1 = 0.f;
#pragma unroll
        for (int ww = 0; ww < 16; ++ww) {
            sqs += smem_f[0 * 1024 + ww * 64 + t];
            G0  += smem_f[1 * 1024 + ww * 64 + t];
            G1  += smem_f[2 * 1024 + ww * 64 + t];
            R0  += smem_f[3 * 1024 + ww * 64 + t];
            R1  += smem_f[4 * 1024 + ww * 64 + t];
        }
        float inv = 1.0f / fmaxf(sqrtf(sqs), FEPS);
        if (n2 < NN) {
            g[2 * (size_t)n2]     = G0 * inv;
            g[2 * (size_t)n2 + 1] = G1 * inv;
            r[2 * (size_t)n2]     = R0 * inv;
            r[2 * (size_t)n2 + 1] = R1 * inv;
        }
    }
}

// layer-2 mean via CSR gather of g, +b2, +lin_r, L2-normalize, log_softmax
__global__ __launch_bounds__(256) void finalize_kernel(
    const int* __restrict__ off, const int* __restrict__ col,
    const float* __restrict__ g, const float* __restrict__ r,
    const float* __restrict__ b2,
    float* __restrict__ out)
{
    int n = blockIdx.x * 256 + threadIdx.x;
    if (n >= NN) return;
    int s0 = off[n], s1 = off[n + 1];
    float z0 = 0.0f, z1 = 0.0f, y0b = 0.0f, y1b = 0.0f;
    int i = s0;
    for (; i + 1 < s1; i += 2) {
        int sa = clampN(col[i]);
        int sb = clampN(col[i + 1]);
        float2 va = *(const float2*)(g + 2 * (size_t)sa);
        float2 vb = *(const float2*)(g + 2 * (size_t)sb);
        z0 += va.x; z1 += va.y;
        y0b += vb.x; y1b += vb.y;
    }
    if (i < s1) {
        int sa = clampN(col[i]);
        float2 va = *(const float2*)(g + 2 * (size_t)sa);
        z0 += va.x; z1 += va.y;
    }
    z0 += y0b; z1 += y1b;
    float ic = 1.0f / fmaxf((float)(s1 - s0), 1.0f);
    z0 = z0 * ic + b2[0] + r[2 * (size_t)n];
    z1 = z1 * ic + b2[1] + r[2 * (size_t)n + 1];
    float d = 1.0f / fmaxf(sqrtf(z0 * z0 + z1 * z1), FEPS);
    float y0 = z0 * d, y1 = z1 * d;
    float m = fmaxf(y0, y1);
    float l = m + logf(__expf(y0 - m) + __expf(y1 - m));
    out[2 * (size_t)n]     = y0 - l;
    out[2 * (size_t)n + 1] = y1 - l;
}

// ---------------------------------------------------------------------------
extern "C" void kernel_launch(void* const* d_in, const int* in_sizes, int n_in,
                              void* d_out, int out_size, void* d_ws, size_t ws_size,
                              hipStream_t stream) {
    // setup_inputs order: x, edge_index, W1_l, b1, W1_r, W2_l, b2, W2_r
    const float* x   = (const float*)d_in[0];
    const int*   ei  = (const int*)d_in[1];
    const float* W1l = (const float*)d_in[2];
    const float* b1  = (const float*)d_in[3];
    const float* W1r = (const float*)d_in[4];
    const float* W2l = (const float*)d_in[5];
    const float* b2  = (const float*)d_in[6];
    const float* W2r = (const float*)d_in[7];

    const int nsb = (NN + 1023) / 1024;  // 98 scan blocks

    float* Wt   = (float*)d_ws;                  // [256*256]
    int*   cnt  = (int*)(Wt + 256 * 256);
    int*   cur  = cnt + NN;
    int*   off  = cur + NN;                      // NN+1
    int*   col  = off + NN + 1;                  // NE
    float* g    = (float*)(col + NE);            // NN*2
    float* r    = g + 2 * (size_t)NN;            // NN*2
    int*   bsum = (int*)(r + 2 * (size_t)NN);    // 128
    int*   flag = bsum + 128;

    int eb = (NE + 255) / 256;
    setup_kernel<<<257, 256, 0, stream>>>(ei, W1l, W1r, Wt, cnt, flag);
    count_kernel<<<eb, 256, 0, stream>>>(ei, flag, cnt);
    scan_a_kernel<<<nsb, 1024, 0, stream>>>(cnt, off, bsum);
    scan_b_kernel<<<1, 128, 0, stream>>>(bsum, off, nsb);
    scan_c_kernel<<<nsb, 1024, 0, stream>>>(bsum, off);
    fill_kernel<<<eb, 256, 0, stream>>>(ei, flag, off, cur, col);
    layer1_kernel<<<(NN + 63) / 64, 1024, 0, stream>>>(off, col, x, Wt, b1,
                                                       W2l, W2r, g, r);
    finalize_kernel<<<(NN + 255) / 256, 256, 0, stream>>>(off, col, g, r, b2,
                                                          (float*)d_out);
}

// Round 9
// 428.686 us; speedup vs baseline: 4.3940x; 1.0184x over previous
//
#include <hip/hip_runtime.h>
#include <hip/hip_fp16.h>

// Problem constants (from reference)
#define NN  100000   // nodes
#define FIN 128      // in features
#define HID 256      // hidden
#define NE  600000   // edges
#define FEPS 1e-12f

// ---------------------------------------------------------------------------
// Workspace layout (~31.1 MB):
//   float Wt[256*256] | half xh[NN*FIN] | int cnt[NN] | cur[NN] | off[NN+1]
//   | col[NE] | float g[NN*2] | r[NN*2] | int bsum[128] | flag[1]
// Evidence log:
//  - R5: ws_size >= 31.1 MB (fast path ran); bf16 FEATURES fail precision:
//    absmax 0.465 from 3.9e-3 source step through 1/||z|| amplification.
//    => fp16 step 6.1e-5 predicts ~0.007 extra error (linear scaling). Self
//    term kept fp32 to halve the quantization surface.
//  - R6: wave-per-node gather REGRESSED (too little MLP per wave).
//  - R7/R8: occupancy 16->32 waves/CU: 507->309->291 us. Occupancy lever
//    exhausted; phase A is ~200 us of gather latency over a 51 MB table.
// ---------------------------------------------------------------------------

__device__ __forceinline__ int clampN(int v) {
    return ((unsigned)v < (unsigned)NN) ? v : 0;
}
__device__ __forceinline__ int ld_src(const int* ei, int e, int f) {
    return f ? ei[2 * e] : ei[e];
}
__device__ __forceinline__ int ld_dst(const int* ei, int e, int f) {
    return f ? ei[2 * (NE + e)] : ei[NE + e];
}

// ---------------------------------------------------------------------------
// Setup (fused): block 0 = int64/int32 detect; blocks 1..256 = weight
// transpose; blocks 257.. = x fp32 -> fp16 (RNE); all blocks zero cnt|cur.
// ---------------------------------------------------------------------------
__global__ __launch_bounds__(256) void setup_kernel(
    const int* __restrict__ ei,
    const float* __restrict__ x,
    const float* __restrict__ W1l, const float* __restrict__ W1r,
    float* __restrict__ Wt, __half* __restrict__ xh,
    int* __restrict__ cnt2 /* cnt|cur, 2*NN */, int* __restrict__ flag)
{
    int b = blockIdx.x;
    int t = threadIdx.x;
    if (b == 0) {
        if (t < 64) {
            // int64 little-endian (<2^31): every odd 32-bit word is 0.
            unsigned long long bal = __ballot(ei[2 * t + 1] != 0);
            if (t == 0) *flag = (bal == 0ULL) ? 1 : 0;
        }
    } else if (b <= 256) {
        int k2 = b - 1;
        float v = (k2 < FIN) ? W1l[(size_t)t * FIN + k2]
                             : W1r[(size_t)t * FIN + (k2 - FIN)];
        Wt[(size_t)k2 * HID + t] = v;
    } else {
        int idx = (b - 257) * 256 + t;           // 8-float group
        if (idx < NN * FIN / 8) {
            const float4* px = (const float4*)(x + (size_t)idx * 8);
            float4 v0 = px[0], v1 = px[1];
            __half2 h0 = __float22half2_rn(make_float2(v0.x, v0.y));
            __half2 h1 = __float22half2_rn(make_float2(v0.z, v0.w));
            __half2 h2 = __float22half2_rn(make_float2(v1.x, v1.y));
            __half2 h3 = __float22half2_rn(make_float2(v1.z, v1.w));
            uint4 u;
            u.x = __builtin_bit_cast(unsigned, h0);
            u.y = __builtin_bit_cast(unsigned, h1);
            u.z = __builtin_bit_cast(unsigned, h2);
            u.w = __builtin_bit_cast(unsigned, h3);
            ((uint4*)xh)[idx] = u;
        }
    }
    for (int idx = b * 256 + t; idx < 2 * NN; idx += gridDim.x * 256)
        cnt2[idx] = 0;
}

// in-degree count
__global__ __launch_bounds__(256) void count_kernel(
    const int* __restrict__ ei, const int* __restrict__ flag,
    int* __restrict__ cnt)
{
    int e = blockIdx.x * 256 + threadIdx.x;
    if (e >= NE) return;
    int f = *flag;
    atomicAdd(cnt + clampN(ld_dst(ei, e, f)), 1);
}

// 3-phase parallel exclusive scan of cnt[NN] -> off[NN+1]
__global__ __launch_bounds__(1024) void scan_a_kernel(
    const int* __restrict__ cnt, int* __restrict__ off, int* __restrict__ bsum)
{
    __shared__ int sm[1024];
    int t = threadIdx.x;
    int idx = blockIdx.x * 1024 + t;
    int v = (idx < NN) ? cnt[idx] : 0;
    sm[t] = v;
    __syncthreads();
    for (int d = 1; d < 1024; d <<= 1) {
        int w = (t >= d) ? sm[t - d] : 0;
        __syncthreads();
        sm[t] += w;
        __syncthreads();
    }
    if (idx < NN) off[idx] = sm[t] - v;
    if (t == 1023) bsum[blockIdx.x] = sm[1023];
}
__global__ __launch_bounds__(128) void scan_b_kernel(
    int* __restrict__ bsum, int* __restrict__ off, int nblocks)
{
    __shared__ int sm[128];
    int t = threadIdx.x;
    int v = (t < nblocks) ? bsum[t] : 0;
    sm[t] = v;
    __syncthreads();
    for (int d = 1; d < 128; d <<= 1) {
        int w = (t >= d) ? sm[t - d] : 0;
        __syncthreads();
        sm[t] += w;
        __syncthreads();
    }
    if (t < nblocks) bsum[t] = sm[t] - v;
    if (t == 0) off[NN] = NE;
}
__global__ __launch_bounds__(1024) void scan_c_kernel(
    const int* __restrict__ bsum, int* __restrict__ off)
{
    int idx = blockIdx.x * 1024 + threadIdx.x;
    if (idx < NN) off[idx] += bsum[blockIdx.x];
}

// place src ids into CSR slots
__global__ __launch_bounds__(256) void fill_kernel(
    const int* __restrict__ ei, const int* __restrict__ flag,
    const int* __restrict__ off, int* __restrict__ cur, int* __restrict__ col)
{
    int e = blockIdx.x * 256 + threadIdx.x;
    if (e >= NE) return;
    int f = *flag;
    int src = clampN(ld_src(ei, e, f));
    int dst = clampN(ld_dst(ei, e, f));
    int p = atomicAdd(cur + dst, 1);
    col[off[dst] + p] = src;
}

// ---------------------------------------------------------------------------
// Fused layer-1 (+ layer-2 projections), LDS-tiled fp32 GEMM.
// 1024 threads/block, 64 nodes/block, 64 KB tile -> 2 blocks/CU = 32 waves/CU.
// HALFX=true: neighbor rows gathered from the fp16 copy (256 B rows, half the
//   L2-miss traffic; accumulation fp32; self row still read from fp32 x).
// Phase A: 16 threads/node, 8 contiguous features; neighbor loop unrolled x4.
// Phase B: 16 waves; wave w owns j-strip [16w,16w+16); o[16] in VGPRs;
//   weight rows wave-uniform -> scalar loads; lane = node.
// Epilogue: bias/relu/L2-norm partials -> LDS overlay -> final g,r.
// ---------------------------------------------------------------------------
template <bool HALFX>
__global__ __launch_bounds__(1024, 8) void layer1_kernel(
    const int* __restrict__ off, const int* __restrict__ col,
    const float* __restrict__ x,    // [NN, FIN] fp32
    const __half* __restrict__ xh,  // [NN, FIN] fp16 copy (HALFX path)
    const float* __restrict__ Wt,   // [256, HID]
    const float* __restrict__ b1,
    const float* __restrict__ W2l, const float* __restrict__ W2r,
    float* __restrict__ g, float* __restrict__ r)
{
    __shared__ float smem_f[256 * 64];   // 64 KB

    const int t  = threadIdx.x;          // 0..1023
    const int nb = blockIdx.x * 64;

    // ---- Phase A: thread-parallel gather/mean ----
    {
        const int n_loc = t >> 4;        // 0..63
        const int ft    = t & 15;        // feature group (8 floats)
        const int fbase = ft * 8;
        const int n     = nb + n_loc;
        const bool valid = (n < NN);

        float a[8];
#pragma unroll
        for (int i = 0; i < 8; ++i) a[i] = 0.0f;

        int s0 = 0, s1 = 0;
        if (valid) { s0 = off[n]; s1 = off[n + 1]; }

        int i = s0;
        if (HALFX) {
            for (; i + 3 < s1; i += 4) {     // 4 independent 16B loads
                int c0 = clampN(col[i]);
                int c1 = clampN(col[i + 1]);
                int c2 = clampN(col[i + 2]);
                int c3 = clampN(col[i + 3]);
                uint4 v0 = *(const uint4*)(xh + (size_t)c0 * FIN + fbase);
                uint4 v1 = *(const uint4*)(xh + (size_t)c1 * FIN + fbase);
                uint4 v2 = *(const uint4*)(xh + (size_t)c2 * FIN + fbase);
                uint4 v3 = *(const uint4*)(xh + (size_t)c3 * FIN + fbase);
#pragma unroll
                for (int u = 0; u < 4; ++u) {
                    unsigned w0 = (&v0.x)[u], w1 = (&v1.x)[u];
                    unsigned w2 = (&v2.x)[u], w3 = (&v3.x)[u];
                    float2 f0 = __half22float2(__builtin_bit_cast(__half2, w0));
                    float2 f1 = __half22float2(__builtin_bit_cast(__half2, w1));
                    float2 f2 = __half22float2(__builtin_bit_cast(__half2, w2));
                    float2 f3 = __half22float2(__builtin_bit_cast(__half2, w3));
                    a[2 * u]     += (f0.x + f1.x) + (f2.x + f3.x);
                    a[2 * u + 1] += (f0.y + f1.y) + (f2.y + f3.y);
                }
            }
            for (; i < s1; ++i) {
                int c0 = clampN(col[i]);
                uint4 v0 = *(const uint4*)(xh + (size_t)c0 * FIN + fbase);
#pragma unroll
                for (int u = 0; u < 4; ++u) {
                    float2 f0 = __half22float2(
                        __builtin_bit_cast(__half2, (&v0.x)[u]));
                    a[2 * u]     += f0.x;
                    a[2 * u + 1] += f0.y;
                }
            }
        } else {
            for (; i + 3 < s1; i += 4) {
                int c0 = clampN(col[i]);
                int c1 = clampN(col[i + 1]);
                int c2 = clampN(col[i + 2]);
                int c3 = clampN(col[i + 3]);
                const float4* p0 = (const float4*)(x + (size_t)c0 * FIN + fbase);
                const float4* p1 = (const float4*)(x + (size_t)c1 * FIN + fbase);
                const float4* p2 = (const float4*)(x + (size_t)c2 * FIN + fbase);
                const float4* p3 = (const float4*)(x + (size_t)c3 * FIN + fbase);
                float4 v00 = p0[0], v01 = p0[1];
                float4 v10 = p1[0], v11 = p1[1];
                float4 v20 = p2[0], v21 = p2[1];
                float4 v30 = p3[0], v31 = p3[1];
                a[0] += (v00.x + v10.x) + (v20.x + v30.x);
                a[1] += (v00.y + v10.y) + (v20.y + v30.y);
                a[2] += (v00.z + v10.z) + (v20.z + v30.z);
                a[3] += (v00.w + v10.w) + (v20.w + v30.w);
                a[4] += (v01.x + v11.x) + (v21.x + v31.x);
                a[5] += (v01.y + v11.y) + (v21.y + v31.y);
                a[6] += (v01.z + v11.z) + (v21.z + v31.z);
                a[7] += (v01.w + v11.w) + (v21.w + v31.w);
            }
            for (; i < s1; ++i) {
                int c0 = clampN(col[i]);
                const float4* p0 = (const float4*)(x + (size_t)c0 * FIN + fbase);
                float4 v00 = p0[0], v01 = p0[1];
                a[0] += v00.x; a[1] += v00.y; a[2] += v00.z; a[3] += v00.w;
                a[4] += v01.x; a[5] += v01.y; a[6] += v01.z; a[7] += v01.w;
            }
        }
        float ic = 1.0f / fmaxf((float)(s1 - s0), 1.0f);
#pragma unroll
        for (int k = 0; k < 8; ++k) {
            int f = fbase + k;
            smem_f[f * 64 + (n_loc ^ ((f >> 3) & 31))] = a[k] * ic;
        }
        // self row: fp32 source (exact), coalesced streaming
        const float4* sp = (const float4*)(x + (size_t)(valid ? n : 0) * FIN + fbase);
        float4 s0v = valid ? sp[0] : make_float4(0.f, 0.f, 0.f, 0.f);
        float4 s1v = valid ? sp[1] : make_float4(0.f, 0.f, 0.f, 0.f);
        float sv[8] = {s0v.x, s0v.y, s0v.z, s0v.w, s1v.x, s1v.y, s1v.z, s1v.w};
#pragma unroll
        for (int k = 0; k < 8; ++k) {
            int f = FIN + fbase + k;
            smem_f[f * 64 + (n_loc ^ ((f >> 3) & 31))] = sv[k];
        }
    }
    __syncthreads();

    // ---- Phase B: 16 waves, wave w owns j in [16w, 16w+16); lane = node ----
    const int w  = __builtin_amdgcn_readfirstlane(t >> 6);  // 0..15
    const int l  = t & 63;
    const int jb = w * 16;

    float o[16];
#pragma unroll
    for (int i = 0; i < 16; ++i) o[i] = 0.0f;

#pragma unroll 1
    for (int k2 = 0; k2 < 2 * FIN; ++k2) {
        float av = smem_f[k2 * 64 + (l ^ ((k2 >> 3) & 31))];
        const float* wrow = Wt + (size_t)k2 * HID + jb;   // wave-uniform
#pragma unroll
        for (int i = 0; i < 16; ++i) o[i] += av * wrow[i];
    }

    // ---- Epilogue: bias, relu, partials over this wave's 16 j's ----
    float sq = 0.f, g0 = 0.f, g1 = 0.f, r0 = 0.f, r1 = 0.f;
    const float* b1w  = b1  + jb;
    const float* w2la = W2l + jb;
    const float* w2lb = W2l + HID + jb;
    const float* w2ra = W2r + jb;
    const float* w2rb = W2r + HID + jb;
#pragma unroll
    for (int i = 0; i < 16; ++i) {
        float oo = o[i] + b1w[i];
        sq += oo * oo;
        float p = fmaxf(oo, 0.0f);           // relu(o/D) = relu(o)/D
        g0 += p * w2la[i];
        g1 += p * w2lb[i];
        r0 += p * w2ra[i];
        r1 += p * w2rb[i];
    }

    __syncthreads();                          // tile dead; reuse as overlay
    smem_f[0 * 1024 + t] = sq;
    smem_f[1 * 1024 + t] = g0;
    smem_f[2 * 1024 + t] = g1;
    smem_f[3 * 1024 + t] = r0;
    smem_f[4 * 1024 + t] = r1;
    __syncthreads();

    if (t < 64) {
        int n2 = nb + t;
        float sqs = 0.f, G0 = 0.f, G1 = 0.f, R0 = 0.f, R1 = 0.f;
#pragma unroll
        for (int ww = 0; ww < 16; ++ww) {
            sqs += smem_f[0 * 1024 + ww * 64 + t];
            G0  += smem_f[1 * 1024 + ww * 64 + t];
            G1  += smem_f[2 * 1024 + ww * 64 + t];
            R0  += smem_f[3 * 1024 + ww * 64 + t];
            R1  += smem_f[4 * 1024 + ww * 64 + t];
        }
        float inv = 1.0f / fmaxf(sqrtf(sqs), FEPS);
        if (n2 < NN) {
            g[2 * (size_t)n2]     = G0 * inv;
            g[2 * (size_t)n2 + 1] = G1 * inv;
            r[2 * (size_t)n2]     = R0 * inv;
            r[2 * (size_t)n2 + 1] = R1 * inv;
        }
    }
}

// layer-2 mean via CSR gather of g, +b2, +lin_r, L2-normalize, log_softmax
__global__ __launch_bounds__(256) void finalize_kernel(
    const int* __restrict__ off, const int* __restrict__ col,
    const float* __restrict__ g, const float* __restrict__ r,
    const float* __restrict__ b2,
    float* __restrict__ out)
{
    int n = blockIdx.x * 256 + threadIdx.x;
    if (n >= NN) return;
    int s0 = off[n], s1 = off[n + 1];
    float z0 = 0.0f, z1 = 0.0f, y0b = 0.0f, y1b = 0.0f;
    int i = s0;
    for (; i + 1 < s1; i += 2) {
        int sa = clampN(col[i]);
        int sb = clampN(col[i + 1]);
        float2 va = *(const float2*)(g + 2 * (size_t)sa);
        float2 vb = *(const float2*)(g + 2 * (size_t)sb);
        z0 += va.x; z1 += va.y;
        y0b += vb.x; y1b += vb.y;
    }
    if (i < s1) {
        int sa = clampN(col[i]);
        float2 va = *(const float2*)(g + 2 * (size_t)sa);
        z0 += va.x; z1 += va.y;
    }
    z0 += y0b; z1 += y1b;
    float ic = 1.0f / fmaxf((float)(s1 - s0), 1.0f);
    z0 = z0 * ic + b2[0] + r[2 * (size_t)n];
    z1 = z1 * ic + b2[1] + r[2 * (size_t)n + 1];
    float d = 1.0f / fmaxf(sqrtf(z0 * z0 + z1 * z1), FEPS);
    float y0 = z0 * d, y1 = z1 * d;
    float m = fmaxf(y0, y1);
    float l = m + logf(__expf(y0 - m) + __expf(y1 - m));
    out[2 * (size_t)n]     = y0 - l;
    out[2 * (size_t)n + 1] = y1 - l;
}

// ---------------------------------------------------------------------------
extern "C" void kernel_launch(void* const* d_in, const int* in_sizes, int n_in,
                              void* d_out, int out_size, void* d_ws, size_t ws_size,
                              hipStream_t stream) {
    // setup_inputs order: x, edge_index, W1_l, b1, W1_r, W2_l, b2, W2_r
    const float* x   = (const float*)d_in[0];
    const int*   ei  = (const int*)d_in[1];
    const float* W1l = (const float*)d_in[2];
    const float* b1  = (const float*)d_in[3];
    const float* W1r = (const float*)d_in[4];
    const float* W2l = (const float*)d_in[5];
    const float* b2  = (const float*)d_in[6];
    const float* W2r = (const float*)d_in[7];

    const int nsb = (NN + 1023) / 1024;  // 98 scan blocks
    const int ncv = (NN * FIN / 8 + 255) / 256;  // 6250 convert blocks

    char* p = (char*)d_ws;
    float* Wt = (float*)p;                p += (size_t)256 * 256 * 4;

    size_t need_fast = (size_t)256 * 256 * 4 + (size_t)NN * FIN * 2 +
                       ((size_t)2 * NN + (NN + 1) + NE + 4 * NN + 128 + 1) * 4;
    bool fast = (ws_size >= need_fast);   // host-side constant: graph-safe

    __half* xh = nullptr;
    if (fast) { xh = (__half*)p; p += (size_t)NN * FIN * 2; }

    int*   cnt  = (int*)p;
    int*   cur  = cnt + NN;
    int*   off  = cur + NN;                      // NN+1
    int*   col  = off + NN + 1;                  // NE
    float* g    = (float*)(col + NE);            // NN*2
    float* r    = g + 2 * (size_t)NN;            // NN*2
    int*   bsum = (int*)(r + 2 * (size_t)NN);    // 128
    int*   flag = bsum + 128;

    int eb = (NE + 255) / 256;
    setup_kernel<<<fast ? (257 + ncv) : 257, 256, 0, stream>>>(
        ei, x, W1l, W1r, Wt, xh, cnt, flag);
    count_kernel<<<eb, 256, 0, stream>>>(ei, flag, cnt);
    scan_a_kernel<<<nsb, 1024, 0, stream>>>(cnt, off, bsum);
    scan_b_kernel<<<1, 128, 0, stream>>>(bsum, off, nsb);
    scan_c_kernel<<<nsb, 1024, 0, stream>>>(bsum, off);
    fill_kernel<<<eb, 256, 0, stream>>>(ei, flag, off, cur, col);
    if (fast)
        layer1_kernel<true><<<(NN + 63) / 64, 1024, 0, stream>>>(
            off, col, x, xh, Wt, b1, W2l, W2r, g, r);
    else
        layer1_kernel<false><<<(NN + 63) / 64, 1024, 0, stream>>>(
            off, col, x, xh, Wt, b1, W2l, W2r, g, r);
    finalize_kernel<<<(NN + 255) / 256, 256, 0, stream>>>(off, col, g, r, b2,
                                                          (float*)d_out);
}